// Round 7
// baseline (12.002 us; speedup 1.0000x reference)
//
#include <hip/hip_runtime.h>
#include <math.h>

#define BATCH  8
#define NPRED  4096
#define MGT    2048
#define UU     4096
#define SPB    8                     // pred-slice blocks per batch
#define NPROD  (BATCH * SPB)         // 64 producer blocks (== one wave of slots)
#define PSLICE (NPRED / SPB)         // 512 preds per block
#define WREG   (PSLICE / 4)          // 128: per-wave compaction region capacity
#define GPT    (MGT / 256)           // 8 gt boxes per thread
#define MAGIC  0xC0FFEE00u
#define STRIDE 16                    // u64 stride -> 128 B per slot (own cache line)

__global__ __launch_bounds__(256) void fused_kernel(
    const float4* __restrict__ pred_boxes,     // [B*N]
    const int2*   __restrict__ pred_classes2,  // [B*N/2]
    const float4* __restrict__ gt_boxes,       // [B*M]
    const float4* __restrict__ union_scores4,  // [U/4]
    const int4*   __restrict__ union_classes4, // [U/4]
    unsigned long long* __restrict__ slots,    // ws: 64 slots, 128 B apart
    float* __restrict__ out)                   // [2] = {max_prob_t, max_iou_t}
{
    __shared__ float4 plist[4][WREG];   // wave-private compaction regions
    __shared__ float  parea[4][WREG];
    __shared__ int    lcnt[4];
    __shared__ float  wmax[4];
    __shared__ float  umax[4];

    const int tid  = threadIdx.x;
    const int blk  = blockIdx.x;        // 0..63
    const int w    = tid >> 6;
    const int lane = tid & 63;
    const int b    = blk >> 3;
    const int psub = blk & 7;

    // ---- issue ALL loads up front (19 independent vmem ops, one latency hop) ----
    const int  cbase = b * (NPRED / 2) + psub * (PSLICE / 2) + tid;  // int2 idx
    const int2 cl    = pred_classes2[cbase];
    const float4 bx0 = pred_boxes[cbase * 2 + 0];
    const float4 bx1 = pred_boxes[cbase * 2 + 1];

    float4 g[GPT];
    #pragma unroll
    for (int k = 0; k < GPT; ++k)
        g[k] = gt_boxes[b * MGT + k * 256 + tid];

    int4   uc[4];
    float4 us[4];
    #pragma unroll
    for (int s = 0; s < 4; ++s) {       // full union arrays, redundantly per block
        uc[s] = union_classes4[s * 256 + tid];
        us[s] = union_scores4[s * 256 + tid];
    }

    float ga[GPT];
    #pragma unroll
    for (int k = 0; k < GPT; ++k)
        ga[k] = (g[k].z - g[k].x) * (g[k].w - g[k].y);   // zeroed invalid gt -> iou 0

    // ---- per-wave compaction (same-wave DS ops are ordered; regions wave-private) ----
    if (lane == 0) lcnt[w] = 0;
    if (cl.x == 0) { int p = atomicAdd(&lcnt[w], 1); plist[w][p] = bx0; parea[w][p] = (bx0.z - bx0.x) * (bx0.w - bx0.y); }
    if (cl.y == 0) { int p = atomicAdd(&lcnt[w], 1); plist[w][p] = bx1; parea[w][p] = (bx1.z - bx1.x) * (bx1.w - bx1.y); }
    __syncthreads();

    // ---- IoU: this thread's 8 gts vs all compacted persons (4 wave regions) ----
    float best[GPT];
    #pragma unroll
    for (int k = 0; k < GPT; ++k) best[k] = 0.0f;

    #pragma unroll
    for (int ww = 0; ww < 4; ++ww) {
        const int cnt = lcnt[ww];            // uniform -> LDS broadcast reads
        for (int j = 0; j < cnt; ++j) {
            const float4 p  = plist[ww][j];
            const float  ap = parea[ww][j];
            #pragma unroll
            for (int k = 0; k < GPT; ++k) {
                float iw = fminf(p.z, g[k].z) - fmaxf(p.x, g[k].x);
                float ih = fminf(p.w, g[k].w) - fmaxf(p.y, g[k].y);
                iw = fmaxf(iw, 0.0f); ih = fmaxf(ih, 0.0f);
                const float inter = iw * ih;
                const float uni   = ap + ga[k] - inter;
                best[k] = fmaxf(best[k], inter * __builtin_amdgcn_rcpf(fmaxf(uni, 1e-9f)));
            }
        }
    }

    float bestv = best[0];
    #pragma unroll
    for (int k = 1; k < GPT; ++k) bestv = fmaxf(bestv, best[k]);

    // ---- union masked max (register data, pure VALU) ----
    float mp = -INFINITY;
    #pragma unroll
    for (int s = 0; s < 4; ++s) {
        if (uc[s].x == 0) mp = fmaxf(mp, us[s].x);
        if (uc[s].y == 0) mp = fmaxf(mp, us[s].y);
        if (uc[s].z == 0) mp = fmaxf(mp, us[s].z);
        if (uc[s].w == 0) mp = fmaxf(mp, us[s].w);
    }

    // ---- wave reductions, then one barrier ----
    #pragma unroll
    for (int off = 32; off >= 1; off >>= 1) {
        bestv = fmaxf(bestv, __shfl_xor(bestv, off));
        mp    = fmaxf(mp,    __shfl_xor(mp,    off));
    }
    if (lane == 0) { wmax[w] = bestv; umax[w] = mp; }
    __syncthreads();

    if (w == 0) {
        // block-level IoU max -> signal own slot immediately
        const float bb = fmaxf(fmaxf(wmax[0], wmax[1]), fmaxf(wmax[2], wmax[3]));
        const unsigned long long myv =
            ((unsigned long long)MAGIC << 32) | (unsigned long long)__float_as_uint(bb);
        if (lane == 0)
            __hip_atomic_store(&slots[blk * STRIDE], myv,
                               __ATOMIC_RELAXED, __HIP_MEMORY_SCOPE_AGENT);
        const float mpb = fmaxf(fmaxf(umax[0], umax[1]), fmaxf(umax[2], umax[3]));

        // Commit our store at the coherence point BEFORE snapshotting:
        // guarantees the last-committing block's snapshot sees all 64 tags.
        asm volatile("s_waitcnt vmcnt(0)" ::: "memory");

        // one-shot snapshot: lane l reads slot l (own block's value from register)
        unsigned long long v = myv;
        if (lane != blk)
            v = __hip_atomic_load(&slots[lane * STRIDE],
                                  __ATOMIC_RELAXED, __HIP_MEMORY_SCOPE_AGENT);

        if (__all((unsigned int)(v >> 32) == MAGIC)) {
            // complete snapshot: slots are write-once per call -> values final
            unsigned int q = (unsigned int)v;            // raw float bits, iou >= 0
            // max over the 8 pred-slices of each batch (lanes 8b..8b+7)
            q = max(q, (unsigned int)__shfl_xor((int)q, 1, 8));
            q = max(q, (unsigned int)__shfl_xor((int)q, 2, 8));
            q = max(q, (unsigned int)__shfl_xor((int)q, 4, 8));
            // fixed-order sum over the 8 batch maxima -> bitwise deterministic
            float s = 0.0f;
            #pragma unroll
            for (int i = 0; i < 8; ++i)
                s += __uint_as_float((unsigned int)__shfl((int)q, 8 * i, 64));
            if (lane == 0) {
                out[0] = mpb;              // identical in every block
                out[1] = s * 0.125f;       // mean over batches
            }
            // reset all slots so the next replay starts from a non-magic state
            __hip_atomic_store(&slots[lane * STRIDE], 0ULL,
                               __ATOMIC_RELAXED, __HIP_MEMORY_SCOPE_AGENT);
        }
        // incomplete snapshot -> someone later (or concurrent) completes; just exit
    }
}

extern "C" void kernel_launch(void* const* d_in, const int* in_sizes, int n_in,
                              void* d_out, int out_size, void* d_ws, size_t ws_size,
                              hipStream_t stream) {
    const float4* pred_boxes    = (const float4*)d_in[0];
    // d_in[1] = pred_scores (unused by the reference result)
    const int2*   pred_classes2 = (const int2*)d_in[2];
    const float4* gt_boxes      = (const float4*)d_in[3];
    const float4* union_scores4 = (const float4*)d_in[4];
    const int4*   union_classes4= (const int4*)d_in[5];
    float* out = (float*)d_out;
    unsigned long long* slots = (unsigned long long*)d_ws;  // 64 x 128 B lines (8 KB)

    fused_kernel<<<NPROD, 256, 0, stream>>>(pred_boxes, pred_classes2, gt_boxes,
                                            union_scores4, union_classes4, slots, out);
}